// Round 3
// baseline (212.575 us; speedup 1.0000x reference)
//
#include <hip/hip_runtime.h>

#define E 2
#define N 512
#define B 64
#define T 12
#define K 64
#define NBR 8   // rows per wave in k_main

// native clang vector for nontemporal 16B stores (HIP float4 is a class type,
// rejected by __builtin_nontemporal_store)
typedef float floatx4 __attribute__((ext_vector_type(4)));

// ---- DPP wave-64 sum (VALU pipe, no DS traffic), broadcast via readlane(63)
template<int CTRL, int RM>
__device__ __forceinline__ float dpp_add(float x) {
    int y = __builtin_amdgcn_update_dpp(0, __float_as_int(x), CTRL, RM, 0xf, true);
    return x + __int_as_float(y);
}
__device__ __forceinline__ float wave_sum64(float x) {
    x = dpp_add<0x111, 0xf>(x);   // row_shr:1
    x = dpp_add<0x112, 0xf>(x);   // row_shr:2
    x = dpp_add<0x114, 0xf>(x);   // row_shr:4
    x = dpp_add<0x118, 0xf>(x);   // row_shr:8
    x = dpp_add<0x142, 0xa>(x);   // row_bcast:15
    x = dpp_add<0x143, 0xc>(x);   // row_bcast:31
    return __int_as_float(__builtin_amdgcn_readlane(__float_as_int(x), 63));
}

__device__ __forceinline__ void nt_store4(float* p, float a, float b, float c, float d) {
    floatx4 v = {a, b, c, d};
    __builtin_nontemporal_store(v, reinterpret_cast<floatx4*>(p));
}

// blocks [0,256): sup (4 n-rows/block); blocks [256,320): nodes for b=blk-256,
// written BOTH row-major (anchor s_loads) and transposed (coalesced col loads).
__global__ __launch_bounds__(512)
void k_prep(const float* __restrict__ supports, const float* __restrict__ uu,
            const float* __restrict__ ss, const float* __restrict__ vv,
            const float* __restrict__ bias, const float* __restrict__ inp,
            float* __restrict__ sup, float* __restrict__ nodes,
            float* __restrict__ nodesT) {
    const int blk = blockIdx.x, tid = threadIdx.x;
    if (blk < 256) {
        const int e = blk >> 7;
        const int n0 = (blk & 127) * 4;
        __shared__ float uls[4][K];
        if (tid < 4 * K) {
            const int j = tid >> 6, k = tid & 63;
            float bb = bias[e * K + k];
            float sp_ = (bb > 0.f) ? (bb + log1pf(expf(-bb))) : log1pf(expf(bb));
            uls[j][k] = uu[(size_t)(e * N + n0 + j) * K + k] * ss[e * K + k] * sp_;
        }
        __syncthreads();
        const int m = tid;
        const float4* vp = reinterpret_cast<const float4*>(vv + (size_t)(e * N + m) * K);
        float accs[4] = {0.f, 0.f, 0.f, 0.f};
#pragma unroll
        for (int i = 0; i < 16; ++i) {
            float4 q = vp[i];
#pragma unroll
            for (int j = 0; j < 4; ++j) {
                const float* w = &uls[j][i * 4];
                accs[j] += w[0] * q.x + w[1] * q.y + w[2] * q.z + w[3] * q.w;
            }
        }
#pragma unroll
        for (int j = 0; j < 4; ++j) {
            const size_t o = (size_t)(e * N + n0 + j) * N + m;
            sup[o] = accs[j] + supports[o];
        }
    } else {
        const int b = blk - 256;   // one block per batch
        const int n = tid;
        float x[T];
        float sq = 0.f;
#pragma unroll
        for (int t = 0; t < T; ++t) {
            float xv = inp[((size_t)(b * T + t) * N + n) * 2];
            x[t] = xv;
            sq += xv * xv;
        }
        float inv = 1.f / fmaxf(sqrtf(sq), 1e-12f);
#pragma unroll
        for (int t = 0; t < T; ++t) {
            float xv = x[t] * inv;
            nodes[((size_t)(b * N) + n) * T + t] = xv;     // row-major
            nodesT[((size_t)(b * T) + t) * N + n] = xv;    // transposed (coalesced)
        }
    }
}

// One wave per block handles 8 output rows x 512 cols. Lane owns 8 columns
// (regs), loops over anchor rows (wave-uniform loads). Zero LDS, zero barriers.
// Output stores are NONTEMPORAL: out is write-once (134 MB stream) and was
// evicting sup/nodesT from the per-XCD L2, turning ~5 MiB of reads into
// O(100 MB) of HBM re-fetches.
__global__ __launch_bounds__(64)
void k_main(const float* __restrict__ sup, const float* __restrict__ nodes,
            const float* __restrict__ nodesT, float* __restrict__ out) {
    const int bi = blockIdx.x;                    // B * (N/NBR) = 4096
    const int b = bi >> 6;
    const int n0 = (bi & 63) * NBR;
    const int lane = threadIdx.x;                 // single wave per block
    const int m0 = lane * 8;

    // 8 columns x 12 t, coalesced from transposed layout (loaded once per wave)
    float x[T][8];
#pragma unroll
    for (int t = 0; t < T; ++t) {
        const float* cp = nodesT + ((size_t)(b * T) + t) * N + m0;
        float4 c0 = *reinterpret_cast<const float4*>(cp);
        float4 c1 = *reinterpret_cast<const float4*>(cp + 4);
        x[t][0] = c0.x; x[t][1] = c0.y; x[t][2] = c0.z; x[t][3] = c0.w;
        x[t][4] = c1.x; x[t][5] = c1.y; x[t][6] = c1.z; x[t][7] = c1.w;
    }

#pragma unroll
    for (int j = 0; j < NBR; ++j) {
        const int n = n0 + j;
        const float* ap = nodes + ((size_t)(b * N) + n) * T;  // wave-uniform
        float4 a0 = *reinterpret_cast<const float4*>(ap);
        float4 a1 = *reinterpret_cast<const float4*>(ap + 4);
        float4 a2 = *reinterpret_cast<const float4*>(ap + 8);
        float a[T] = {a0.x, a0.y, a0.z, a0.w, a1.x, a1.y, a1.z, a1.w,
                      a2.x, a2.y, a2.z, a2.w};

        const float* s0p = sup + (size_t)n * N + m0;
        const float* s1p = s0p + (size_t)N * N;
        float4 sA = *reinterpret_cast<const float4*>(s0p);
        float4 sB = *reinterpret_cast<const float4*>(s0p + 4);
        float4 sC = *reinterpret_cast<const float4*>(s1p);
        float4 sD = *reinterpret_cast<const float4*>(s1p + 4);
        float sp0[8] = {sA.x, sA.y, sA.z, sA.w, sB.x, sB.y, sB.z, sB.w};
        float sp1[8] = {sC.x, sC.y, sC.z, sC.w, sD.x, sD.y, sD.z, sD.w};

        float v0[8], v1[8];
        float p0 = 0.f, p1 = 0.f;
#pragma unroll
        for (int k = 0; k < 8; ++k) {
            float dot = 0.f;
#pragma unroll
            for (int t = 0; t < T; ++t) dot = fmaf(x[t][k], a[t], dot);
            // rows are unit-norm: d2 = |xn|^2+|xm|^2-2 dot = 2-2dot (clamped)
            float d2 = fmaxf(2.f - 2.f * dot, 0.f);
            float f = __expf(-sqrtf(d2)) + 1.f;
            v0[k] = fmaxf(sp0[k] * f, 0.f);
            v1[k] = fmaxf(sp1[k] * f, 0.f);
            p0 += v0[k];
            p1 += v1[k];
        }
        float inv0 = 1.f / fmaxf(wave_sum64(p0), 1e-12f);
        float inv1 = 1.f / fmaxf(wave_sum64(p1), 1e-12f);

        float* o0 = out + ((size_t)(b * N) + n) * N + m0;
        float* o1 = o0 + (size_t)B * N * N;
        nt_store4(o0,     v0[0] * inv0, v0[1] * inv0, v0[2] * inv0, v0[3] * inv0);
        nt_store4(o0 + 4, v0[4] * inv0, v0[5] * inv0, v0[6] * inv0, v0[7] * inv0);
        nt_store4(o1,     v1[0] * inv1, v1[1] * inv1, v1[2] * inv1, v1[3] * inv1);
        nt_store4(o1 + 4, v1[4] * inv1, v1[5] * inv1, v1[6] * inv1, v1[7] * inv1);
    }
}

extern "C" void kernel_launch(void* const* d_in, const int* in_sizes, int n_in,
                              void* d_out, int out_size, void* d_ws, size_t ws_size,
                              hipStream_t stream) {
    const float* supports = (const float*)d_in[0];  // [E,N,N] fp32
    const float* uu       = (const float*)d_in[1];  // [E,N,K]
    const float* ss       = (const float*)d_in[2];  // [E,K]
    const float* vv       = (const float*)d_in[3];  // [E,N,K]
    const float* bias     = (const float*)d_in[4];  // [E,K]
    const float* inp      = (const float*)d_in[5];  // [B,T,N,2]
    float* out = (float*)d_out;                     // [E,B,N,N] fp32

    float* sup    = (float*)d_ws;                       // 2 MiB
    float* nodes  = sup + (size_t)E * N * N;            // 1.5 MiB
    float* nodesT = nodes + (size_t)B * N * T;          // 1.5 MiB

    k_prep<<<256 + B, 512, 0, stream>>>(supports, uu, ss, vv, bias, inp,
                                        sup, nodes, nodesT);
    k_main<<<B * (N / NBR), 64, 0, stream>>>(sup, nodes, nodesT, out);
}

// Round 4
// 164.331 us; speedup vs baseline: 1.2936x; 1.2936x over previous
//
#include <hip/hip_runtime.h>

#define E 2
#define N 512
#define B 64
#define T 12
#define K 64

// ---- DPP wave-64 sum (VALU pipe, no DS traffic), broadcast via readlane(63)
template<int CTRL, int RM>
__device__ __forceinline__ float dpp_add(float x) {
    int y = __builtin_amdgcn_update_dpp(0, __float_as_int(x), CTRL, RM, 0xf, true);
    return x + __int_as_float(y);
}
__device__ __forceinline__ float wave_sum64(float x) {
    x = dpp_add<0x111, 0xf>(x);   // row_shr:1
    x = dpp_add<0x112, 0xf>(x);   // row_shr:2
    x = dpp_add<0x114, 0xf>(x);   // row_shr:4
    x = dpp_add<0x118, 0xf>(x);   // row_shr:8
    x = dpp_add<0x142, 0xa>(x);   // row_bcast:15
    x = dpp_add<0x143, 0xc>(x);   // row_bcast:31
    return __int_as_float(__builtin_amdgcn_readlane(__float_as_int(x), 63));
}

// blocks [0,256): sup (4 n-rows/block); blocks [256,320): nodes for b=blk-256,
// written BOTH row-major (unused by k_main now, kept identical) and transposed.
__global__ __launch_bounds__(512)
void k_prep(const float* __restrict__ supports, const float* __restrict__ uu,
            const float* __restrict__ ss, const float* __restrict__ vv,
            const float* __restrict__ bias, const float* __restrict__ inp,
            float* __restrict__ sup, float* __restrict__ nodes,
            float* __restrict__ nodesT) {
    const int blk = blockIdx.x, tid = threadIdx.x;
    if (blk < 256) {
        const int e = blk >> 7;
        const int n0 = (blk & 127) * 4;
        __shared__ float uls[4][K];
        if (tid < 4 * K) {
            const int j = tid >> 6, k = tid & 63;
            float bb = bias[e * K + k];
            float sp_ = (bb > 0.f) ? (bb + log1pf(expf(-bb))) : log1pf(expf(bb));
            uls[j][k] = uu[(size_t)(e * N + n0 + j) * K + k] * ss[e * K + k] * sp_;
        }
        __syncthreads();
        const int m = tid;
        const float4* vp = reinterpret_cast<const float4*>(vv + (size_t)(e * N + m) * K);
        float accs[4] = {0.f, 0.f, 0.f, 0.f};
#pragma unroll
        for (int i = 0; i < 16; ++i) {
            float4 q = vp[i];
#pragma unroll
            for (int j = 0; j < 4; ++j) {
                const float* w = &uls[j][i * 4];
                accs[j] += w[0] * q.x + w[1] * q.y + w[2] * q.z + w[3] * q.w;
            }
        }
#pragma unroll
        for (int j = 0; j < 4; ++j) {
            const size_t o = (size_t)(e * N + n0 + j) * N + m;
            sup[o] = accs[j] + supports[o];
        }
    } else {
        const int b = blk - 256;   // one block per batch
        const int n = tid;
        float x[T];
        float sq = 0.f;
#pragma unroll
        for (int t = 0; t < T; ++t) {
            float xv = inp[((size_t)(b * T + t) * N + n) * 2];
            x[t] = xv;
            sq += xv * xv;
        }
        float inv = 1.f / fmaxf(sqrtf(sq), 1e-12f);
#pragma unroll
        for (int t = 0; t < T; ++t) {
            float xv = x[t] * inv;
            nodes[((size_t)(b * N) + n) * T + t] = xv;     // row-major
            nodesT[((size_t)(b * T) + t) * N + n] = xv;    // transposed (coalesced)
        }
    }
}

// 4 waves/block; wave w owns rows [n0blk + 8w, +8), lane owns 8 columns.
// Loop-interchanged: t outer, dot[8][8] accumulators persistent (64 VGPR),
// x streamed per-t (no 96-reg x tile -> VGPR <= 128 -> 4 waves/SIMD).
// Anchor values staged in a 1.5 KB LDS tile, read as wave-uniform broadcasts.
__global__ __launch_bounds__(256, 4)
void k_main(const float* __restrict__ sup, const float* __restrict__ nodesT,
            float* __restrict__ out) {
    const int bi = blockIdx.x;                    // B * (N/32) = 1024
    const int b = bi >> 4;
    const int n0blk = (bi & 15) * 32;
    const int wave = __builtin_amdgcn_readfirstlane((int)threadIdx.x >> 6);
    const int lane = threadIdx.x & 63;
    const int m0 = lane * 8;

    // anchor rows for this block: aT[t][r] = normalized x of row (n0blk+r) at t
    __shared__ float aT[T][32];
    for (int idx = threadIdx.x; idx < T * 32; idx += 256) {
        const int t = idx >> 5, r = idx & 31;
        aT[t][r] = nodesT[((size_t)(b * T) + t) * N + n0blk + r];
    }
    __syncthreads();

    float dot[8][8];
#pragma unroll
    for (int j = 0; j < 8; ++j)
#pragma unroll
        for (int k = 0; k < 8; ++k) dot[j][k] = 0.f;

    const float* xbase = nodesT + (size_t)(b * T) * N + m0;
#pragma unroll 2
    for (int t = 0; t < T; ++t) {
        float4 x4a = *reinterpret_cast<const float4*>(xbase + (size_t)t * N);
        float4 x4b = *reinterpret_cast<const float4*>(xbase + (size_t)t * N + 4);
        const float* ap = &aT[t][wave * 8];          // wave-uniform -> broadcast
        float4 a4a = *reinterpret_cast<const float4*>(ap);
        float4 a4b = *reinterpret_cast<const float4*>(ap + 4);
        const float xs[8] = {x4a.x, x4a.y, x4a.z, x4a.w, x4b.x, x4b.y, x4b.z, x4b.w};
        const float as[8] = {a4a.x, a4a.y, a4a.z, a4a.w, a4b.x, a4b.y, a4b.z, a4b.w};
#pragma unroll
        for (int j = 0; j < 8; ++j)
#pragma unroll
            for (int k = 0; k < 8; ++k)
                dot[j][k] = fmaf(xs[k], as[j], dot[j][k]);
    }

#pragma unroll
    for (int j = 0; j < 8; ++j) {
        const int n = n0blk + wave * 8 + j;
        const float* s0p = sup + (size_t)n * N + m0;
        const float* s1p = s0p + (size_t)N * N;
        float4 sA = *reinterpret_cast<const float4*>(s0p);
        float4 sB = *reinterpret_cast<const float4*>(s0p + 4);
        float4 sC = *reinterpret_cast<const float4*>(s1p);
        float4 sD = *reinterpret_cast<const float4*>(s1p + 4);
        float sp0[8] = {sA.x, sA.y, sA.z, sA.w, sB.x, sB.y, sB.z, sB.w};
        float sp1[8] = {sC.x, sC.y, sC.z, sC.w, sD.x, sD.y, sD.z, sD.w};

        float v0[8], v1[8];
        float p0 = 0.f, p1 = 0.f;
#pragma unroll
        for (int k = 0; k < 8; ++k) {
            // rows are unit-norm: d2 = 2 - 2*dot (clamped)
            float d2 = fmaxf(2.f - 2.f * dot[j][k], 0.f);
            float f = __expf(-sqrtf(d2)) + 1.f;
            v0[k] = fmaxf(sp0[k] * f, 0.f);
            v1[k] = fmaxf(sp1[k] * f, 0.f);
            p0 += v0[k];
            p1 += v1[k];
        }
        float inv0 = 1.f / fmaxf(wave_sum64(p0), 1e-12f);
        float inv1 = 1.f / fmaxf(wave_sum64(p1), 1e-12f);

        float* o0 = out + ((size_t)(b * N) + n) * N + m0;
        float* o1 = o0 + (size_t)B * N * N;
        *reinterpret_cast<float4*>(o0) =
            make_float4(v0[0] * inv0, v0[1] * inv0, v0[2] * inv0, v0[3] * inv0);
        *reinterpret_cast<float4*>(o0 + 4) =
            make_float4(v0[4] * inv0, v0[5] * inv0, v0[6] * inv0, v0[7] * inv0);
        *reinterpret_cast<float4*>(o1) =
            make_float4(v1[0] * inv1, v1[1] * inv1, v1[2] * inv1, v1[3] * inv1);
        *reinterpret_cast<float4*>(o1 + 4) =
            make_float4(v1[4] * inv1, v1[5] * inv1, v1[6] * inv1, v1[7] * inv1);
    }
}

extern "C" void kernel_launch(void* const* d_in, const int* in_sizes, int n_in,
                              void* d_out, int out_size, void* d_ws, size_t ws_size,
                              hipStream_t stream) {
    const float* supports = (const float*)d_in[0];  // [E,N,N] fp32
    const float* uu       = (const float*)d_in[1];  // [E,N,K]
    const float* ss       = (const float*)d_in[2];  // [E,K]
    const float* vv       = (const float*)d_in[3];  // [E,N,K]
    const float* bias     = (const float*)d_in[4];  // [E,K]
    const float* inp      = (const float*)d_in[5];  // [B,T,N,2]
    float* out = (float*)d_out;                     // [E,B,N,N] fp32

    float* sup    = (float*)d_ws;                       // 2 MiB
    float* nodes  = sup + (size_t)E * N * N;            // 1.5 MiB
    float* nodesT = nodes + (size_t)B * N * T;          // 1.5 MiB

    k_prep<<<256 + B, 512, 0, stream>>>(supports, uu, ss, vv, bias, inp,
                                        sup, nodes, nodesT);
    k_main<<<B * (N / 32), 256, 0, stream>>>(sup, nodesT, out);
}